// Round 2
// baseline (396.154 us; speedup 1.0000x reference)
//
#include <hip/hip_runtime.h>

#define NEG_TWOPI -6.28318530717958647692f
#define INV_N (1.0f / 4096.0f)

__device__ __forceinline__ void bf(float& ar, float& ai, float& br, float& bi,
                                   float s, float cs) {
    float tr = cs * br - s * bi;
    float ti = cs * bi + s * br;
    br = ar - tr; bi = ai - ti;
    ar = ar + tr; ai = ai + ti;
}

__device__ __forceinline__ void tw(int k, float wk, float* s, float* cs) {
    __sincosf(NEG_TWOPI * ((float)k * INV_N) * wk, s, cs);
}

// Two-round 16 KB ownership exchange: consecutive-16 rows -> stride-4 rows.
// Register set per round chosen by the cyclic-invariant predicate
// (pb + (m>>2) + (m&3)) & 1, which guarantees the registers a thread flushes
// in a round are exactly the ones it refills in that round (no extra VGPRs).
// Write slot:  srow = (pb<<3) + ((m>>2)<<1) + ((m&3)>>1)
// Read  slot:  srow = ((m>>2)<<3) + ((m&3)<<1) + (pb>>1)   (row pb+4m's owner)
__device__ __forceinline__ void exchange(float2* tile, float (&ar)[16],
                                         float (&ai)[16], int pb, int c) {
#pragma unroll
    for (int par = 0; par < 2; ++par) {
#pragma unroll
        for (int m = 0; m < 16; ++m) {
            if (((pb + (m >> 2) + (m & 3)) & 1) == par) {
                int srow = (pb << 3) + (((m >> 2) << 1) | ((m & 3) >> 1));
                tile[srow * 64 + c] = make_float2(ar[m], ai[m]);
            }
        }
        __syncthreads();
#pragma unroll
        for (int m = 0; m < 16; ++m) {
            if (((pb + (m >> 2) + (m & 3)) & 1) == par) {
                int srow = ((m >> 2) << 3) + ((m & 3) << 1) + (pb >> 1);
                float2 v = tile[srow * 64 + c];
                ar[m] = v.x; ai[m] = v.y;
            }
        }
        if (par == 0) __syncthreads();
    }
}

// Kernel A: stages step=2..64 (butterflies within aligned 64-row blocks).
// Direct register I/O, all-w prefetch at entry, 16 KB exchange (8 blocks/CU).
__global__ __launch_bounds__(256, 8) void fft_lo(const float* __restrict__ x,
                                                 const float* __restrict__ w,
                                                 float2* __restrict__ dst2,
                                                 unsigned dst_lim2) {
    __shared__ __align__(16) float2 tile[32 * 64];   // 16 KB, exchange only
    const int t   = threadIdx.x;
    const int c   = t & 63;
    const int pb  = t >> 6;
    const int c0  = (blockIdx.x & 63) << 6;
    const int r0  = (blockIdx.x >> 6) << 6;
    const int src_r0 = r0 ^ 2048;      // initial permutation: new[i] = old[i^2048]
    const int col = c0 + c;

    // ---- prefetch ALL w values (independent of data; overlaps everything) ----
    float wp1[7];
#pragma unroll
    for (int i = 0; i < 7; ++i)
        wp1[i] = w[(size_t)(256 * (i + 1)) * 4096 + col];
    float w2a[4], w2b[8];
#pragma unroll
    for (int i = 0; i < 4; ++i)
        w2a[i] = w[(size_t)((pb + 4 * i) * 128) * 4096 + col];
#pragma unroll
    for (int i = 0; i < 8; ++i)
        w2b[i] = w[(size_t)((pb + 4 * i) * 64) * 4096 + col];

    // ---- direct loads: rows 16*pb+m, imag = 0 (x read once -> nontemporal) ----
    float ar[16], ai[16];
#pragma unroll
    for (int m = 0; m < 16; ++m) {
        ar[m] = __builtin_nontemporal_load(&x[(size_t)(src_r0 + 16 * pb + m) * 4096 + col]);
        ai[m] = 0.f;
    }

    // ---- phase-1 twiddles (7 sincos, shared across h; s1[0] = identity) ----
    float s1[8], c1[8];
    s1[0] = 0.f; c1[0] = 1.f;
#pragma unroll
    for (int i = 1; i < 8; ++i)
        tw(256 * i, wp1[i - 1], &s1[i], &c1[i]);

    // ---- phase 1: h = 1,2,4,8 (steps 2..16); twiddle index = r*8/h ----
#pragma unroll
    for (int h = 1; h <= 8; h <<= 1) {
        const int step = h << 1;
#pragma unroll
        for (int r = 0; r < h; ++r) {
            const int ti = r * (8 / h);
            const float s = s1[ti], cs = c1[ti];
#pragma unroll
            for (int b = 0; b < 8 / h; ++b) {
                const int mt = b * step + r;
                bf(ar[mt], ai[mt], ar[mt + h], ai[mt + h], s, cs);
            }
        }
    }

    // ---- phase-2 twiddles BEFORE the barriers (hide sincos under the wait) ----
    float s2a[4], c2a[4], s2b[8], c2b[8];
#pragma unroll
    for (int i = 0; i < 4; ++i)
        tw((pb + 4 * i) * 128, w2a[i], &s2a[i], &c2a[i]);
#pragma unroll
    for (int i = 0; i < 8; ++i)
        tw((pb + 4 * i) * 64, w2b[i], &s2b[i], &c2b[i]);

    // ---- ownership exchange: consecutive-16 -> stride-4 (16 KB, 3 barriers) --
    exchange(tile, ar, ai, pb, c);

    // ---- phase 2: step 32 (pairs m,m+4) then step 64 (pairs m,m+8) ----
#pragma unroll
    for (int rm = 0; rm < 4; ++rm) {
#pragma unroll
        for (int b = 0; b < 2; ++b) {
            const int mt = b * 8 + rm;
            bf(ar[mt], ai[mt], ar[mt + 4], ai[mt + 4], s2a[rm], c2a[rm]);
        }
    }
#pragma unroll
    for (int m = 0; m < 8; ++m)
        bf(ar[m], ai[m], ar[m + 8], ai[m + 8], s2b[m], c2b[m]);

    // ---- direct stores: rows r0 + pb + 4*m (512 B/wave, coalesced) ----
#pragma unroll
    for (int m = 0; m < 16; ++m) {
        size_t gi = (size_t)(r0 + pb + 4 * m) * 4096 + col;
        if (gi < dst_lim2) dst2[gi] = make_float2(ar[m], ai[m]);
    }
}

// Kernel B: stages step=128..4096 on rows {rres + 64*j}. Same structure.
template <int REAL_OUT>
__global__ __launch_bounds__(256, 8) void fft_hi(const float* __restrict__ w,
                                                 const float2* __restrict__ src2,
                                                 float2* __restrict__ dstc,
                                                 float* __restrict__ dstr,
                                                 unsigned dst_lim) {
    __shared__ __align__(16) float2 tile[32 * 64];   // 16 KB, exchange only
    const int t    = threadIdx.x;
    const int c    = t & 63;
    const int pb   = t >> 6;
    const int c0   = (blockIdx.x & 63) << 6;
    const int rres = blockIdx.x >> 6;
    const int col  = c0 + c;

    // ---- prefetch ALL w values (27 per thread, all independent) ----
    float wp1, wp2[2], wp4[4], wp8[8];
    wp1 = w[(size_t)(rres * 32) * 4096 + col];
#pragma unroll
    for (int r = 0; r < 2; ++r)
        wp2[r] = w[(size_t)((rres + 64 * r) * 16) * 4096 + col];
#pragma unroll
    for (int r = 0; r < 4; ++r)
        wp4[r] = w[(size_t)((rres + 64 * r) * 8) * 4096 + col];
#pragma unroll
    for (int r = 0; r < 8; ++r)
        wp8[r] = w[(size_t)((rres + 64 * r) * 4) * 4096 + col];
    float w2a[4], w2b[8];
#pragma unroll
    for (int i = 0; i < 4; ++i)
        w2a[i] = w[(size_t)((rres + 64 * (pb + 4 * i)) * 2) * 4096 + col];
#pragma unroll
    for (int i = 0; i < 8; ++i)
        w2b[i] = w[(size_t)(rres + 64 * (pb + 4 * i)) * 4096 + col];

    // ---- direct loads: global rows rres + 64*(16*pb+m) (512 B/wave) ----
    float ar[16], ai[16];
#pragma unroll
    for (int m = 0; m < 16; ++m) {
        float2 v = src2[(size_t)(rres + 64 * (16 * pb + m)) * 4096 + col];
        ar[m] = v.x; ai[m] = v.y;
    }

    // ---- phase 1: global steps 128, 256, 512, 1024 ----
    {
        float s, cs;
        tw(rres * 32, wp1, &s, &cs);
#pragma unroll
        for (int b = 0; b < 8; ++b)
            bf(ar[2 * b], ai[2 * b], ar[2 * b + 1], ai[2 * b + 1], s, cs);
    }
#pragma unroll
    for (int r = 0; r < 2; ++r) {
        float s, cs;
        tw((rres + 64 * r) * 16, wp2[r], &s, &cs);
#pragma unroll
        for (int b = 0; b < 4; ++b) {
            const int mt = b * 4 + r;
            bf(ar[mt], ai[mt], ar[mt + 2], ai[mt + 2], s, cs);
        }
    }
#pragma unroll
    for (int r = 0; r < 4; ++r) {
        float s, cs;
        tw((rres + 64 * r) * 8, wp4[r], &s, &cs);
#pragma unroll
        for (int b = 0; b < 2; ++b) {
            const int mt = b * 8 + r;
            bf(ar[mt], ai[mt], ar[mt + 4], ai[mt + 4], s, cs);
        }
    }
#pragma unroll
    for (int r = 0; r < 8; ++r) {
        float s, cs;
        tw((rres + 64 * r) * 4, wp8[r], &s, &cs);
        bf(ar[r], ai[r], ar[r + 8], ai[r + 8], s, cs);
    }

    // ---- phase-2 twiddles before the barriers ----
    float s2a[4], c2a[4], s2b[8], c2b[8];
#pragma unroll
    for (int i = 0; i < 4; ++i)
        tw((rres + 64 * (pb + 4 * i)) * 2, w2a[i], &s2a[i], &c2a[i]);
#pragma unroll
    for (int i = 0; i < 8; ++i)
        tw(rres + 64 * (pb + 4 * i), w2b[i], &s2b[i], &c2b[i]);

    // ---- ownership exchange (16 KB, 3 barriers) ----
    exchange(tile, ar, ai, pb, c);

    // ---- phase 2: global steps 2048 (m,m+4) and 4096 (m,m+8) ----
#pragma unroll
    for (int rm = 0; rm < 4; ++rm) {
#pragma unroll
        for (int b = 0; b < 2; ++b) {
            const int mt = b * 8 + rm;
            bf(ar[mt], ai[mt], ar[mt + 4], ai[mt + 4], s2a[rm], c2a[rm]);
        }
    }
#pragma unroll
    for (int m = 0; m < 8; ++m)
        bf(ar[m], ai[m], ar[m + 8], ai[m + 8], s2b[m], c2b[m]);

    // ---- direct stores: rows rres + 64*(pb+4*m) ----
    if (REAL_OUT) {
#pragma unroll
        for (int m = 0; m < 16; ++m) {
            size_t gi = (size_t)(rres + 64 * (pb + 4 * m)) * 4096 + col;
            if (gi < dst_lim) __builtin_nontemporal_store(ar[m], &dstr[gi]);
        }
    } else {
#pragma unroll
        for (int m = 0; m < 16; ++m) {
            size_t gi = (size_t)(rres + 64 * (pb + 4 * m)) * 4096 + col;
            if (gi < dst_lim) dstc[gi] = make_float2(ar[m], ai[m]);
        }
    }
}

extern "C" void kernel_launch(void* const* d_in, const int* in_sizes, int n_in,
                              void* d_out, int out_size, void* d_ws, size_t ws_size,
                              hipStream_t stream) {
    const float* x = (const float*)d_in[0];
    const float* w = (const float*)d_in[1];
    const long long NN = 4096LL * 4096LL;

    if ((long long)out_size >= 2 * NN) {
        // d_out = interleaved complex (2*N*N floats): compute in-place.
        float2* o2 = (float2*)d_out;
        unsigned lim2 = (unsigned)(out_size / 2);          // float2 units
        fft_lo<<<4096, 256, 0, stream>>>(x, w, o2, lim2);
        fft_hi<0><<<4096, 256, 0, stream>>>(w, o2, o2, nullptr, lim2);
    } else {
        // Confirmed world: d_out = N*N floats (real part). Complex
        // intermediate in d_ws (>= 2*N*N floats, verified earlier rounds).
        float2* ws2 = (float2*)d_ws;
        unsigned ws_lim2 = (unsigned)(ws_size / 8);        // bytes -> float2 units
        unsigned out_lim = (unsigned)out_size;             // float units
        fft_lo<<<4096, 256, 0, stream>>>(x, w, ws2, ws_lim2);
        fft_hi<1><<<4096, 256, 0, stream>>>(w, (const float2*)ws2, nullptr,
                                            (float*)d_out, out_lim);
    }
}

// Round 3
// 203.106 us; speedup vs baseline: 1.9505x; 1.9505x over previous
//
#include <hip/hip_runtime.h>

#define NEG_TWOPI -6.28318530717958647692f
#define INV_N (1.0f / 4096.0f)

__device__ __forceinline__ void bf(float& ar, float& ai, float& br, float& bi,
                                   float s, float cs) {
    float tr = cs * br - s * bi;
    float ti = cs * bi + s * br;
    br = ar - tr; bi = ai - ti;
    ar = ar + tr; ai = ai + ti;
}

__device__ __forceinline__ void tw(int k, float wk, float* s, float* cs) {
    __sincosf(NEG_TWOPI * ((float)k * INV_N) * wk, s, cs);
}

// Two-round 16 KB ownership exchange: consecutive-16 rows -> stride-4 rows.
// Register set per round chosen by the cyclic-invariant predicate
// (pb + (m>>2) + (m&3)) & 1: the registers a thread flushes in a round are
// exactly the ones it refills in that round (no extra live VGPRs).
// Write slot:  srow = (pb<<3) + ((m>>2)<<1) + ((m&3)>>1)
// Read  slot:  srow = ((m>>2)<<3) + ((m&3)<<1) + (pb>>1)   (row pb+4m's owner)
__device__ __forceinline__ void exchange(float2* tile, float (&ar)[16],
                                         float (&ai)[16], int pb, int c) {
#pragma unroll
    for (int par = 0; par < 2; ++par) {
#pragma unroll
        for (int m = 0; m < 16; ++m) {
            if (((pb + (m >> 2) + (m & 3)) & 1) == par) {
                int srow = (pb << 3) + (((m >> 2) << 1) | ((m & 3) >> 1));
                tile[srow * 64 + c] = make_float2(ar[m], ai[m]);
            }
        }
        __syncthreads();
#pragma unroll
        for (int m = 0; m < 16; ++m) {
            if (((pb + (m >> 2) + (m & 3)) & 1) == par) {
                int srow = ((m >> 2) << 3) + ((m & 3) << 1) + (pb >> 1);
                float2 v = tile[srow * 64 + c];
                ar[m] = v.x; ai[m] = v.y;
            }
        }
        if (par == 0) __syncthreads();
    }
}

// Kernel A: stages step=2..64 (butterflies within aligned 64-row blocks).
// Direct register I/O, all-w prefetch at entry, 16 KB exchange.
// NOTE: no min-waves clause — forcing 8 waves/EU caps VGPR at 64 and spills
// (round-2 regression: VGPR 32, WRITE_SIZE 350 MB of scratch traffic).
__global__ __launch_bounds__(256) void fft_lo(const float* __restrict__ x,
                                              const float* __restrict__ w,
                                              float2* __restrict__ dst2,
                                              unsigned dst_lim2) {
    __shared__ __align__(16) float2 tile[32 * 64];   // 16 KB, exchange only
    const int t   = threadIdx.x;
    const int c   = t & 63;
    const int pb  = t >> 6;
    const int c0  = (blockIdx.x & 63) << 6;
    const int r0  = (blockIdx.x >> 6) << 6;
    const int src_r0 = r0 ^ 2048;      // initial permutation: new[i] = old[i^2048]
    const int col = c0 + c;

    // ---- prefetch ALL w values (independent of data; overlaps everything) ----
    float wp1[7];
#pragma unroll
    for (int i = 0; i < 7; ++i)
        wp1[i] = w[(size_t)(256 * (i + 1)) * 4096 + col];
    float w2a[4], w2b[8];
#pragma unroll
    for (int i = 0; i < 4; ++i)
        w2a[i] = w[(size_t)((pb + 4 * i) * 128) * 4096 + col];
#pragma unroll
    for (int i = 0; i < 8; ++i)
        w2b[i] = w[(size_t)((pb + 4 * i) * 64) * 4096 + col];

    // ---- direct loads: rows 16*pb+m, imag = 0 (x read once -> nontemporal) ----
    float ar[16], ai[16];
#pragma unroll
    for (int m = 0; m < 16; ++m) {
        ar[m] = __builtin_nontemporal_load(&x[(size_t)(src_r0 + 16 * pb + m) * 4096 + col]);
        ai[m] = 0.f;
    }

    // ---- phase-1 twiddles (7 sincos, shared across h; s1[0] = identity) ----
    float s1[8], c1[8];
    s1[0] = 0.f; c1[0] = 1.f;
#pragma unroll
    for (int i = 1; i < 8; ++i)
        tw(256 * i, wp1[i - 1], &s1[i], &c1[i]);

    // ---- phase 1: h = 1,2,4,8 (steps 2..16); twiddle index = r*8/h ----
#pragma unroll
    for (int h = 1; h <= 8; h <<= 1) {
        const int step = h << 1;
#pragma unroll
        for (int r = 0; r < h; ++r) {
            const int ti = r * (8 / h);
            const float s = s1[ti], cs = c1[ti];
#pragma unroll
            for (int b = 0; b < 8 / h; ++b) {
                const int mt = b * step + r;
                bf(ar[mt], ai[mt], ar[mt + h], ai[mt + h], s, cs);
            }
        }
    }

    // ---- phase-2 twiddles BEFORE the barriers (hide sincos under the wait) ----
    float s2a[4], c2a[4], s2b[8], c2b[8];
#pragma unroll
    for (int i = 0; i < 4; ++i)
        tw((pb + 4 * i) * 128, w2a[i], &s2a[i], &c2a[i]);
#pragma unroll
    for (int i = 0; i < 8; ++i)
        tw((pb + 4 * i) * 64, w2b[i], &s2b[i], &c2b[i]);

    // ---- ownership exchange: consecutive-16 -> stride-4 (16 KB, 3 barriers) --
    exchange(tile, ar, ai, pb, c);

    // ---- phase 2: step 32 (pairs m,m+4) then step 64 (pairs m,m+8) ----
#pragma unroll
    for (int rm = 0; rm < 4; ++rm) {
#pragma unroll
        for (int b = 0; b < 2; ++b) {
            const int mt = b * 8 + rm;
            bf(ar[mt], ai[mt], ar[mt + 4], ai[mt + 4], s2a[rm], c2a[rm]);
        }
    }
#pragma unroll
    for (int m = 0; m < 8; ++m)
        bf(ar[m], ai[m], ar[m + 8], ai[m + 8], s2b[m], c2b[m]);

    // ---- direct stores: rows r0 + pb + 4*m (512 B/wave, coalesced) ----
#pragma unroll
    for (int m = 0; m < 16; ++m) {
        size_t gi = (size_t)(r0 + pb + 4 * m) * 4096 + col;
        if (gi < dst_lim2) dst2[gi] = make_float2(ar[m], ai[m]);
    }
}

// Kernel B: stages step=128..4096 on rows {rres + 64*j}. Same structure.
template <int REAL_OUT>
__global__ __launch_bounds__(256) void fft_hi(const float* __restrict__ w,
                                              const float2* __restrict__ src2,
                                              float2* __restrict__ dstc,
                                              float* __restrict__ dstr,
                                              unsigned dst_lim) {
    __shared__ __align__(16) float2 tile[32 * 64];   // 16 KB, exchange only
    const int t    = threadIdx.x;
    const int c    = t & 63;
    const int pb   = t >> 6;
    const int c0   = (blockIdx.x & 63) << 6;
    const int rres = blockIdx.x >> 6;
    const int col  = c0 + c;

    // ---- prefetch ALL w values (27 per thread, all independent) ----
    float wp1, wp2[2], wp4[4], wp8[8];
    wp1 = w[(size_t)(rres * 32) * 4096 + col];
#pragma unroll
    for (int r = 0; r < 2; ++r)
        wp2[r] = w[(size_t)((rres + 64 * r) * 16) * 4096 + col];
#pragma unroll
    for (int r = 0; r < 4; ++r)
        wp4[r] = w[(size_t)((rres + 64 * r) * 8) * 4096 + col];
#pragma unroll
    for (int r = 0; r < 8; ++r)
        wp8[r] = w[(size_t)((rres + 64 * r) * 4) * 4096 + col];
    float w2a[4], w2b[8];
#pragma unroll
    for (int i = 0; i < 4; ++i)
        w2a[i] = w[(size_t)((rres + 64 * (pb + 4 * i)) * 2) * 4096 + col];
#pragma unroll
    for (int i = 0; i < 8; ++i)
        w2b[i] = w[(size_t)(rres + 64 * (pb + 4 * i)) * 4096 + col];

    // ---- direct loads: global rows rres + 64*(16*pb+m) (512 B/wave) ----
    float ar[16], ai[16];
#pragma unroll
    for (int m = 0; m < 16; ++m) {
        float2 v = src2[(size_t)(rres + 64 * (16 * pb + m)) * 4096 + col];
        ar[m] = v.x; ai[m] = v.y;
    }

    // ---- phase 1: global steps 128, 256, 512, 1024 ----
    {
        float s, cs;
        tw(rres * 32, wp1, &s, &cs);
#pragma unroll
        for (int b = 0; b < 8; ++b)
            bf(ar[2 * b], ai[2 * b], ar[2 * b + 1], ai[2 * b + 1], s, cs);
    }
#pragma unroll
    for (int r = 0; r < 2; ++r) {
        float s, cs;
        tw((rres + 64 * r) * 16, wp2[r], &s, &cs);
#pragma unroll
        for (int b = 0; b < 4; ++b) {
            const int mt = b * 4 + r;
            bf(ar[mt], ai[mt], ar[mt + 2], ai[mt + 2], s, cs);
        }
    }
#pragma unroll
    for (int r = 0; r < 4; ++r) {
        float s, cs;
        tw((rres + 64 * r) * 8, wp4[r], &s, &cs);
#pragma unroll
        for (int b = 0; b < 2; ++b) {
            const int mt = b * 8 + r;
            bf(ar[mt], ai[mt], ar[mt + 4], ai[mt + 4], s, cs);
        }
    }
#pragma unroll
    for (int r = 0; r < 8; ++r) {
        float s, cs;
        tw((rres + 64 * r) * 4, wp8[r], &s, &cs);
        bf(ar[r], ai[r], ar[r + 8], ai[r + 8], s, cs);
    }

    // ---- phase-2 twiddles before the barriers ----
    float s2a[4], c2a[4], s2b[8], c2b[8];
#pragma unroll
    for (int i = 0; i < 4; ++i)
        tw((rres + 64 * (pb + 4 * i)) * 2, w2a[i], &s2a[i], &c2a[i]);
#pragma unroll
    for (int i = 0; i < 8; ++i)
        tw(rres + 64 * (pb + 4 * i), w2b[i], &s2b[i], &c2b[i]);

    // ---- ownership exchange (16 KB, 3 barriers) ----
    exchange(tile, ar, ai, pb, c);

    // ---- phase 2: global steps 2048 (m,m+4) and 4096 (m,m+8) ----
#pragma unroll
    for (int rm = 0; rm < 4; ++rm) {
#pragma unroll
        for (int b = 0; b < 2; ++b) {
            const int mt = b * 8 + rm;
            bf(ar[mt], ai[mt], ar[mt + 4], ai[mt + 4], s2a[rm], c2a[rm]);
        }
    }
#pragma unroll
    for (int m = 0; m < 8; ++m)
        bf(ar[m], ai[m], ar[m + 8], ai[m + 8], s2b[m], c2b[m]);

    // ---- direct stores: rows rres + 64*(pb+4*m) ----
    if (REAL_OUT) {
#pragma unroll
        for (int m = 0; m < 16; ++m) {
            size_t gi = (size_t)(rres + 64 * (pb + 4 * m)) * 4096 + col;
            if (gi < dst_lim) __builtin_nontemporal_store(ar[m], &dstr[gi]);
        }
    } else {
#pragma unroll
        for (int m = 0; m < 16; ++m) {
            size_t gi = (size_t)(rres + 64 * (pb + 4 * m)) * 4096 + col;
            if (gi < dst_lim) dstc[gi] = make_float2(ar[m], ai[m]);
        }
    }
}

extern "C" void kernel_launch(void* const* d_in, const int* in_sizes, int n_in,
                              void* d_out, int out_size, void* d_ws, size_t ws_size,
                              hipStream_t stream) {
    const float* x = (const float*)d_in[0];
    const float* w = (const float*)d_in[1];
    const long long NN = 4096LL * 4096LL;

    if ((long long)out_size >= 2 * NN) {
        // d_out = interleaved complex (2*N*N floats): compute in-place.
        float2* o2 = (float2*)d_out;
        unsigned lim2 = (unsigned)(out_size / 2);          // float2 units
        fft_lo<<<4096, 256, 0, stream>>>(x, w, o2, lim2);
        fft_hi<0><<<4096, 256, 0, stream>>>(w, o2, o2, nullptr, lim2);
    } else {
        // Confirmed world: d_out = N*N floats (real part). Complex
        // intermediate in d_ws (>= 2*N*N floats, verified earlier rounds).
        float2* ws2 = (float2*)d_ws;
        unsigned ws_lim2 = (unsigned)(ws_size / 8);        // bytes -> float2 units
        unsigned out_lim = (unsigned)out_size;             // float units
        fft_lo<<<4096, 256, 0, stream>>>(x, w, ws2, ws_lim2);
        fft_hi<1><<<4096, 256, 0, stream>>>(w, (const float2*)ws2, nullptr,
                                            (float*)d_out, out_lim);
    }
}

// Round 4
// 202.054 us; speedup vs baseline: 1.9606x; 1.0052x over previous
//
#include <hip/hip_runtime.h>

#define INV_N (1.0f / 4096.0f)

__device__ __forceinline__ void bf(float& ar, float& ai, float& br, float& bi,
                                   float s, float cs) {
    float tr = cs * br - s * bi;
    float ti = cs * bi + s * br;
    br = ar - tr; bi = ai - ti;
    ar = ar + tr; ai = ai + ti;
}

// Twiddle via native trans pipe. angle = -2pi*(k/4096)*wk radians
// => rev = -(k/4096)*wk revolutions. (float)k*INV_N is exact (pow2 scale).
// v_fract + v_sin/v_cos (input in revolutions) = 4 instrs vs ~45 for ocml
// sincos with software range reduction (round-3 post-mortem: VALUBusy
// arithmetic showed ~45 instrs/call).
__device__ __forceinline__ void tw(int k, float wk, float* s, float* cs) {
    float rev = (float)k * (-INV_N) * wk;
    rev = __builtin_amdgcn_fractf(rev);          // [0,1), handles negatives
    *s  = __builtin_amdgcn_sinf(rev);            // sin(2*pi*rev)
    *cs = __builtin_amdgcn_cosf(rev);            // cos(2*pi*rev)
}

// Two-round 16 KB ownership exchange: consecutive-16 rows -> stride-4 rows.
// Register set per round chosen by the cyclic-invariant predicate
// (pb + (m>>2) + (m&3)) & 1: the registers a thread flushes in a round are
// exactly the ones it refills in that round (no extra live VGPRs).
// Write slot:  srow = (pb<<3) + ((m>>2)<<1) + ((m&3)>>1)
// Read  slot:  srow = ((m>>2)<<3) + ((m&3)<<1) + (pb>>1)   (row pb+4m's owner)
__device__ __forceinline__ void exchange(float2* tile, float (&ar)[16],
                                         float (&ai)[16], int pb, int c) {
#pragma unroll
    for (int par = 0; par < 2; ++par) {
#pragma unroll
        for (int m = 0; m < 16; ++m) {
            if (((pb + (m >> 2) + (m & 3)) & 1) == par) {
                int srow = (pb << 3) + (((m >> 2) << 1) | ((m & 3) >> 1));
                tile[srow * 64 + c] = make_float2(ar[m], ai[m]);
            }
        }
        __syncthreads();
#pragma unroll
        for (int m = 0; m < 16; ++m) {
            if (((pb + (m >> 2) + (m & 3)) & 1) == par) {
                int srow = ((m >> 2) << 3) + ((m & 3) << 1) + (pb >> 1);
                float2 v = tile[srow * 64 + c];
                ar[m] = v.x; ai[m] = v.y;
            }
        }
        if (par == 0) __syncthreads();
    }
}

// Kernel A: stages step=2..64 (butterflies within aligned 64-row blocks).
// Direct register I/O, all-w prefetch at entry, 16 KB exchange.
// NOTE: no min-waves clause — forcing 8 waves/EU caps VGPR at 64 and spills
// (round-2 regression: VGPR 32, WRITE_SIZE 350 MB of scratch traffic).
__global__ __launch_bounds__(256) void fft_lo(const float* __restrict__ x,
                                              const float* __restrict__ w,
                                              float2* __restrict__ dst2,
                                              unsigned dst_lim2) {
    __shared__ __align__(16) float2 tile[32 * 64];   // 16 KB, exchange only
    const int t   = threadIdx.x;
    const int c   = t & 63;
    const int pb  = t >> 6;
    const int c0  = (blockIdx.x & 63) << 6;
    const int r0  = (blockIdx.x >> 6) << 6;
    const int src_r0 = r0 ^ 2048;      // initial permutation: new[i] = old[i^2048]
    const int col = c0 + c;

    // ---- prefetch ALL w values (independent of data; overlaps everything) ----
    float wp1[7];
#pragma unroll
    for (int i = 0; i < 7; ++i)
        wp1[i] = w[(size_t)(256 * (i + 1)) * 4096 + col];
    float w2a[4], w2b[8];
#pragma unroll
    for (int i = 0; i < 4; ++i)
        w2a[i] = w[(size_t)((pb + 4 * i) * 128) * 4096 + col];
#pragma unroll
    for (int i = 0; i < 8; ++i)
        w2b[i] = w[(size_t)((pb + 4 * i) * 64) * 4096 + col];

    // ---- direct loads: rows 16*pb+m, imag = 0 (x read once -> nontemporal) ----
    float ar[16], ai[16];
#pragma unroll
    for (int m = 0; m < 16; ++m) {
        ar[m] = __builtin_nontemporal_load(&x[(size_t)(src_r0 + 16 * pb + m) * 4096 + col]);
        ai[m] = 0.f;
    }

    // ---- phase-1 twiddles (7 sincos, shared across h; s1[0] = identity) ----
    float s1[8], c1[8];
    s1[0] = 0.f; c1[0] = 1.f;
#pragma unroll
    for (int i = 1; i < 8; ++i)
        tw(256 * i, wp1[i - 1], &s1[i], &c1[i]);

    // ---- phase 1: h = 1,2,4,8 (steps 2..16); twiddle index = r*8/h ----
#pragma unroll
    for (int h = 1; h <= 8; h <<= 1) {
        const int step = h << 1;
#pragma unroll
        for (int r = 0; r < h; ++r) {
            const int ti = r * (8 / h);
            const float s = s1[ti], cs = c1[ti];
#pragma unroll
            for (int b = 0; b < 8 / h; ++b) {
                const int mt = b * step + r;
                bf(ar[mt], ai[mt], ar[mt + h], ai[mt + h], s, cs);
            }
        }
    }

    // ---- phase-2 twiddles BEFORE the barriers (hide sincos under the wait) ----
    float s2a[4], c2a[4], s2b[8], c2b[8];
#pragma unroll
    for (int i = 0; i < 4; ++i)
        tw((pb + 4 * i) * 128, w2a[i], &s2a[i], &c2a[i]);
#pragma unroll
    for (int i = 0; i < 8; ++i)
        tw((pb + 4 * i) * 64, w2b[i], &s2b[i], &c2b[i]);

    // ---- ownership exchange: consecutive-16 -> stride-4 (16 KB, 3 barriers) --
    exchange(tile, ar, ai, pb, c);

    // ---- phase 2: step 32 (pairs m,m+4) then step 64 (pairs m,m+8) ----
#pragma unroll
    for (int rm = 0; rm < 4; ++rm) {
#pragma unroll
        for (int b = 0; b < 2; ++b) {
            const int mt = b * 8 + rm;
            bf(ar[mt], ai[mt], ar[mt + 4], ai[mt + 4], s2a[rm], c2a[rm]);
        }
    }
#pragma unroll
    for (int m = 0; m < 8; ++m)
        bf(ar[m], ai[m], ar[m + 8], ai[m + 8], s2b[m], c2b[m]);

    // ---- direct stores: rows r0 + pb + 4*m (512 B/wave, coalesced) ----
#pragma unroll
    for (int m = 0; m < 16; ++m) {
        size_t gi = (size_t)(r0 + pb + 4 * m) * 4096 + col;
        if (gi < dst_lim2) dst2[gi] = make_float2(ar[m], ai[m]);
    }
}

// Kernel B: stages step=128..4096 on rows {rres + 64*j}. Same structure.
template <int REAL_OUT>
__global__ __launch_bounds__(256) void fft_hi(const float* __restrict__ w,
                                              const float2* __restrict__ src2,
                                              float2* __restrict__ dstc,
                                              float* __restrict__ dstr,
                                              unsigned dst_lim) {
    __shared__ __align__(16) float2 tile[32 * 64];   // 16 KB, exchange only
    const int t    = threadIdx.x;
    const int c    = t & 63;
    const int pb   = t >> 6;
    const int c0   = (blockIdx.x & 63) << 6;
    const int rres = blockIdx.x >> 6;
    const int col  = c0 + c;

    // ---- prefetch ALL w values (27 per thread, all independent) ----
    float wp1, wp2[2], wp4[4], wp8[8];
    wp1 = w[(size_t)(rres * 32) * 4096 + col];
#pragma unroll
    for (int r = 0; r < 2; ++r)
        wp2[r] = w[(size_t)((rres + 64 * r) * 16) * 4096 + col];
#pragma unroll
    for (int r = 0; r < 4; ++r)
        wp4[r] = w[(size_t)((rres + 64 * r) * 8) * 4096 + col];
#pragma unroll
    for (int r = 0; r < 8; ++r)
        wp8[r] = w[(size_t)((rres + 64 * r) * 4) * 4096 + col];
    float w2a[4], w2b[8];
#pragma unroll
    for (int i = 0; i < 4; ++i)
        w2a[i] = w[(size_t)((rres + 64 * (pb + 4 * i)) * 2) * 4096 + col];
#pragma unroll
    for (int i = 0; i < 8; ++i)
        w2b[i] = w[(size_t)(rres + 64 * (pb + 4 * i)) * 4096 + col];

    // ---- direct loads: global rows rres + 64*(16*pb+m) (512 B/wave) ----
    float ar[16], ai[16];
#pragma unroll
    for (int m = 0; m < 16; ++m) {
        float2 v = src2[(size_t)(rres + 64 * (16 * pb + m)) * 4096 + col];
        ar[m] = v.x; ai[m] = v.y;
    }

    // ---- phase 1: global steps 128, 256, 512, 1024 ----
    {
        float s, cs;
        tw(rres * 32, wp1, &s, &cs);
#pragma unroll
        for (int b = 0; b < 8; ++b)
            bf(ar[2 * b], ai[2 * b], ar[2 * b + 1], ai[2 * b + 1], s, cs);
    }
#pragma unroll
    for (int r = 0; r < 2; ++r) {
        float s, cs;
        tw((rres + 64 * r) * 16, wp2[r], &s, &cs);
#pragma unroll
        for (int b = 0; b < 4; ++b) {
            const int mt = b * 4 + r;
            bf(ar[mt], ai[mt], ar[mt + 2], ai[mt + 2], s, cs);
        }
    }
#pragma unroll
    for (int r = 0; r < 4; ++r) {
        float s, cs;
        tw((rres + 64 * r) * 8, wp4[r], &s, &cs);
#pragma unroll
        for (int b = 0; b < 2; ++b) {
            const int mt = b * 8 + r;
            bf(ar[mt], ai[mt], ar[mt + 4], ai[mt + 4], s, cs);
        }
    }
#pragma unroll
    for (int r = 0; r < 8; ++r) {
        float s, cs;
        tw((rres + 64 * r) * 4, wp8[r], &s, &cs);
        bf(ar[r], ai[r], ar[r + 8], ai[r + 8], s, cs);
    }

    // ---- phase-2 twiddles before the barriers ----
    float s2a[4], c2a[4], s2b[8], c2b[8];
#pragma unroll
    for (int i = 0; i < 4; ++i)
        tw((rres + 64 * (pb + 4 * i)) * 2, w2a[i], &s2a[i], &c2a[i]);
#pragma unroll
    for (int i = 0; i < 8; ++i)
        tw(rres + 64 * (pb + 4 * i), w2b[i], &s2b[i], &c2b[i]);

    // ---- ownership exchange (16 KB, 3 barriers) ----
    exchange(tile, ar, ai, pb, c);

    // ---- phase 2: global steps 2048 (m,m+4) and 4096 (m,m+8) ----
#pragma unroll
    for (int rm = 0; rm < 4; ++rm) {
#pragma unroll
        for (int b = 0; b < 2; ++b) {
            const int mt = b * 8 + rm;
            bf(ar[mt], ai[mt], ar[mt + 4], ai[mt + 4], s2a[rm], c2a[rm]);
        }
    }
#pragma unroll
    for (int m = 0; m < 8; ++m)
        bf(ar[m], ai[m], ar[m + 8], ai[m + 8], s2b[m], c2b[m]);

    // ---- direct stores: rows rres + 64*(pb+4*m) ----
    if (REAL_OUT) {
#pragma unroll
        for (int m = 0; m < 16; ++m) {
            size_t gi = (size_t)(rres + 64 * (pb + 4 * m)) * 4096 + col;
            if (gi < dst_lim) __builtin_nontemporal_store(ar[m], &dstr[gi]);
        }
    } else {
#pragma unroll
        for (int m = 0; m < 16; ++m) {
            size_t gi = (size_t)(rres + 64 * (pb + 4 * m)) * 4096 + col;
            if (gi < dst_lim) dstc[gi] = make_float2(ar[m], ai[m]);
        }
    }
}

extern "C" void kernel_launch(void* const* d_in, const int* in_sizes, int n_in,
                              void* d_out, int out_size, void* d_ws, size_t ws_size,
                              hipStream_t stream) {
    const float* x = (const float*)d_in[0];
    const float* w = (const float*)d_in[1];
    const long long NN = 4096LL * 4096LL;

    if ((long long)out_size >= 2 * NN) {
        // d_out = interleaved complex (2*N*N floats): compute in-place.
        float2* o2 = (float2*)d_out;
        unsigned lim2 = (unsigned)(out_size / 2);          // float2 units
        fft_lo<<<4096, 256, 0, stream>>>(x, w, o2, lim2);
        fft_hi<0><<<4096, 256, 0, stream>>>(w, o2, o2, nullptr, lim2);
    } else {
        // Confirmed world: d_out = N*N floats (real part). Complex
        // intermediate in d_ws (>= 2*N*N floats, verified earlier rounds).
        float2* ws2 = (float2*)d_ws;
        unsigned ws_lim2 = (unsigned)(ws_size / 8);        // bytes -> float2 units
        unsigned out_lim = (unsigned)out_size;             // float units
        fft_lo<<<4096, 256, 0, stream>>>(x, w, ws2, ws_lim2);
        fft_hi<1><<<4096, 256, 0, stream>>>(w, (const float2*)ws2, nullptr,
                                            (float*)d_out, out_lim);
    }
}